// Round 7
// baseline (298.904 us; speedup 1.0000x reference)
//
#include <hip/hip_runtime.h>
#include <hip/hip_bf16.h>
#include <stdint.h>
#include <stddef.h>

// DCNv2 forward: B=4, H=W=96, C=256, F=256, K=9 (3x3, same, stride1, dil1), DG=1.
// R7: fused sampling+GEMM, second attempt. R5 failed fetch-bound (313MB) from (a) 2x
//   sampling duplication (grid.y=2), (b) half-line 32-ch gathers, (c) no XCD locality.
//   Fixes: N=256 single tile (M=48, grid 768 = 3.0/CU); BK=64 full-line slices; XCD
//   swizzle lt=(bx&7)*96+(bx>>3) so each XCD L2 sees one ~2.4MB xp slice; skewed B slots
//   (conflict-free MFMA B reads under global_load_lds's forced-dense layout); A rows
//   padded to 144B. cols[] (170MB) and k_sample/k_gemm are gone.

namespace {
constexpr int H  = 96, W = 96, C = 256, F = 256;
constexpr int HP = 98;            // padded spatial dim (1-px zero halo)
constexpr int NP = 4 * 96 * 96;   // 36864 output pixels
constexpr int KC = 9 * 256;       // 2304 = GEMM K

constexpr int NB_PAD  = 4 * HP * HP / 8;       // 4802 blocks, 8 px each
constexpr int NB_OMW  = 9 * 32;                // 288
constexpr int NB_WT   = (KC / 64) * (F / 64);  // 144
constexpr int NB_ZERO = NP * 32 * 4 / 4096;    // 1152
}

typedef __attribute__((ext_vector_type(8))) short bf16x8;
typedef __attribute__((ext_vector_type(4))) float floatx4;

__device__ __forceinline__ void load_lds16(const void* g, void* l) {
  __builtin_amdgcn_global_load_lds((const __attribute__((address_space(1))) void*)g,
                                   (__attribute__((address_space(3))) void*)l,
                                   16, 0, 0);
}

__device__ __forceinline__ uint32_t pk2(float lo, float hi) {   // v_cvt_pk_bf16_f32 (RNE)
  __hip_bfloat162 t = __float22bfloat162_rn(float2{lo, hi});
  return *reinterpret_cast<uint32_t*>(&t);
}

__device__ __forceinline__ void acc8(uint4 v, float w, float* a) {
  a[0] += w * __uint_as_float(v.x << 16); a[1] += w * __uint_as_float(v.x & 0xffff0000u);
  a[2] += w * __uint_as_float(v.y << 16); a[3] += w * __uint_as_float(v.y & 0xffff0000u);
  a[4] += w * __uint_as_float(v.z << 16); a[5] += w * __uint_as_float(v.z & 0xffff0000u);
  a[6] += w * __uint_as_float(v.w << 16); a[7] += w * __uint_as_float(v.w & 0xffff0000u);
}

// ---------------- k_prep: pad + omw + wt + pOm-zero in one dispatch ----------------
__global__ __launch_bounds__(256) void k_prep(const float* __restrict__ x,
                                              const float* __restrict__ omk,
                                              const float* __restrict__ kern,
                                              uint4* __restrict__ xp4,
                                              __hip_bfloat16* __restrict__ wom,
                                              __hip_bfloat16* __restrict__ wt,
                                              float4* __restrict__ pOmz) {
  __shared__ float t[64][65];
  const int bi = blockIdx.x, tid = threadIdx.x;

  if (bi < NB_PAD) {                       // ---- pad: 8 px/block, 8 ch/thread ----
    const int sub = tid >> 5, cid = tid & 31;
    const int pp  = bi * 8 + sub;
    const int b   = pp / (HP * HP);
    const int r   = pp % (HP * HP);
    const int y   = r / HP, xq = r % HP;
    uint4 o = {0u, 0u, 0u, 0u};
    if (y >= 1 && y <= H && xq >= 1 && xq <= W) {
      const float* src = x + ((size_t)((b * H + (y - 1)) * W + (xq - 1))) * C + cid * 8;
      const float4 v0 = *(const float4*)src;
      const float4 v1 = *(const float4*)(src + 4);
      o.x = pk2(v0.x, v0.y); o.y = pk2(v0.z, v0.w);
      o.z = pk2(v1.x, v1.y); o.w = pk2(v1.z, v1.w);
    }
    xp4[(size_t)pp * 32 + cid] = o;
  } else if (bi < NB_PAD + NB_OMW) {       // ---- omw: [9*256][27] -> [32][2304] ----
    const int i  = bi - NB_PAD;
    const int kk = i / 32, oc = i % 32;
    float v = (oc < 27) ? omk[(size_t)(kk * 256 + tid) * 27 + oc] : 0.f;
    wom[(size_t)oc * KC + kk * 256 + tid] = __float2bfloat16(v);
  } else if (bi < NB_PAD + NB_OMW + NB_WT) {  // ---- wt: [KC][F] -> [F][KC] bf16 ----
    const int j   = bi - NB_PAD - NB_OMW;
    const int kc0 = (j % (KC / 64)) * 64, f0 = (j / (KC / 64)) * 64;
    const int rr = tid >> 6, cc = tid & 63;
#pragma unroll
    for (int i = 0; i < 16; ++i)
      t[rr * 16 + i][cc] = kern[(size_t)(kc0 + rr * 16 + i) * F + f0 + cc];
    __syncthreads();
#pragma unroll
    for (int i = 0; i < 16; ++i) {
      const int frow = rr * 16 + i;
      wt[(size_t)(f0 + frow) * KC + kc0 + cc] = __float2bfloat16(t[cc][frow]);
    }
  } else {                                 // ---- pOm zero ----
    const int j = bi - NB_PAD - NB_OMW - NB_WT;
    pOmz[(size_t)j * 256 + tid] = (float4){0.f, 0.f, 0.f, 0.f};
  }
}

// ---------------- k_omgemm: implicit-im2col MFMA GEMM, 128(M)x32(N), split-K x6 ----------------
__global__ __launch_bounds__(256) void k_omgemm(const __hip_bfloat16* __restrict__ xp,
                                                const __hip_bfloat16* __restrict__ wom,
                                                float* __restrict__ pOm) {
  __shared__ __align__(16) char lds[10240];
  const int tid  = threadIdx.x;
  const int m0   = blockIdx.x * 128;
  const int s    = blockIdx.y;
  const int lane = tid & 63, wave = tid >> 6;
  const int quad = lane >> 4, l16 = lane & 15;

  const int kp = tid & 3;
  const __hip_bfloat16* abase[2];
#pragma unroll
  for (int j = 0; j < 2; ++j) {
    const int row = (tid >> 2) + j * 64;
    const int p = m0 + row;
    const int b = p / (H * W);
    const int hw = p % (H * W);
    const int h = hw / W, w = hw % W;
    abase[j] = xp + ((size_t)(b * HP + h) * HP + w) * C + kp * 8;
  }
  const __hip_bfloat16* bbase = wom + (size_t)(tid >> 2) * KC + kp * 8;

  floatx4 acc[2][2];
#pragma unroll
  for (int i = 0; i < 2; ++i)
#pragma unroll
    for (int j = 0; j < 2; ++j) acc[i][j] = (floatx4){0.f, 0.f, 0.f, 0.f};

  const int kbeg = s * 384;
#pragma unroll 1
  for (int k0 = kbeg; k0 < kbeg + 384; k0 += 32) {
    const int kk = k0 >> 8;
    const int c0 = k0 & 255;
    const int kh = kk / 3, kw = kk % 3;
    const int aoff = (kh * HP + kw) * C + c0;

    __syncthreads();
    load_lds16(abase[0] + aoff, &lds[tid * 16]);
    load_lds16(abase[1] + aoff, &lds[4096 + tid * 16]);
    if (tid < 128) load_lds16(bbase + k0, &lds[8192 + tid * 16]);
    __syncthreads();

    bf16x8 af[2], bfr[2];
#pragma unroll
    for (int mt = 0; mt < 2; ++mt)
      af[mt] = *(const bf16x8*)&lds[((wave * 32 + mt * 16 + l16) * 32 + quad * 8) * 2];
#pragma unroll
    for (int nt = 0; nt < 2; ++nt)
      bfr[nt] = *(const bf16x8*)&lds[8192 + ((nt * 16 + l16) * 32 + quad * 8) * 2];
#pragma unroll
    for (int mt = 0; mt < 2; ++mt)
#pragma unroll
      for (int nt = 0; nt < 2; ++nt)
        acc[mt][nt] = __builtin_amdgcn_mfma_f32_16x16x32_bf16(af[mt], bfr[nt], acc[mt][nt], 0, 0, 0);
  }

#pragma unroll
  for (int mt = 0; mt < 2; ++mt)
#pragma unroll
    for (int nt = 0; nt < 2; ++nt) {
      const int gm = m0 + wave * 32 + mt * 16 + quad * 4;
      const int gn = nt * 16 + l16;
#pragma unroll
      for (int r = 0; r < 4; ++r)
        __hip_atomic_fetch_add(&pOm[(size_t)(gm + r) * 32 + gn], acc[mt][nt][r],
                               __ATOMIC_RELAXED, __HIP_MEMORY_SCOPE_AGENT);
    }
}

// ---------------- k_fused: sampling fused into 48(M) x 256(N) MFMA GEMM, BK=64 ----------------
// One tile = 48 px (half image row), all 256 output channels -> sampling done once per px.
// Per K-step (64 ch of one (kh,kw)): 192 threads sample A [48][64] into LDS (full-line
// uint4x2 gathers), all 256 stage B via global_load_lds into skewed slots; 4 waves MFMA.
__global__ __launch_bounds__(256, 3) void k_fused(const uint4* __restrict__ xpu,
                                                  const float* __restrict__ pOm,
                                                  const float* __restrict__ omb,
                                                  const __hip_bfloat16* __restrict__ Bt,
                                                  const float* __restrict__ bias,
                                                  float* __restrict__ out) {
  __shared__ __align__(16) char  s_a[48 * 144];   // A [48 px][64 ch] bf16, 144B row stride
  __shared__ __align__(16) char  s_b[32768];      // B 2048 slots; slot(c,n)=c*256+((n+2c)&255)
  __shared__ float2 s_ow[48 * 9 * 4];             // per (px,k,corner): {uint4-offset, wgt*mask}

  const int tid  = threadIdx.x;
  const int bx   = blockIdx.x;
  const int lt   = (bx & 7) * 96 + (bx >> 3);     // XCD-contiguous tile id (locality heuristic)
  const int m0   = lt * 48;
  const int lane = tid & 63, wave = tid >> 6;
  const int quad = lane >> 4, l16 = lane & 15;

  // ---- setup: offsets/weights for 48 px x 9 k ----
#pragma unroll 1
  for (int i = tid; i < 48 * 9; i += 256) {
    const int ps = i % 48, k = i / 48;
    const int p  = m0 + ps;
    const int b  = p / (H * W);
    const int hw = p % (H * W);
    const int h = hw / W, w = hw % W;
    const float dy = omb[2 * k]     + pOm[(size_t)p * 32 + 2 * k];
    const float dx = omb[2 * k + 1] + pOm[(size_t)p * 32 + 2 * k + 1];
    const float mv = omb[18 + k]    + pOm[(size_t)p * 32 + 18 + k];
    const float m  = 2.f / (1.f + __expf(-mv));
    const float sy = (float)(h - 1 + k / 3) + dy;
    const float sx = (float)(w - 1 + k % 3) + dx;
    const float y0f = floorf(sy), x0f = floorf(sx);
    const float fy = sy - y0f, fx = sx - x0f;
    const int y0 = (int)y0f, x0 = (int)x0f;
#pragma unroll
    for (int c2 = 0; c2 < 4; ++c2) {
      const int dy2 = c2 >> 1, dx2 = c2 & 1;
      const int yi = y0 + dy2, xi = x0 + dx2;
      const bool valid = (yi >= 0) & (yi < H) & (xi >= 0) & (xi < W);
      const float wgt = valid ? (dy2 ? fy : 1.f - fy) * (dx2 ? fx : 1.f - fx) * m : 0.f;
      const int yc = min(max(yi + 1, 0), HP - 1);
      const int xc = min(max(xi + 1, 0), HP - 1);
      const int off = ((b * HP + yc) * HP + xc) * 32;   // uint4 units
      s_ow[(ps * 9 + k) * 4 + c2] = float2{__int_as_float(off), wgt};
    }
  }

  floatx4 acc[3][4];
#pragma unroll
  for (int i = 0; i < 3; ++i)
#pragma unroll
    for (int j = 0; j < 4; ++j) acc[i][j] = (floatx4){0.f, 0.f, 0.f, 0.f};

  const int ps = tid >> 2, grp = tid & 3;   // sampling unit: (pixel, 16-ch group), tid<192

#pragma unroll 1
  for (int k0 = 0; k0 < KC; k0 += 64) {
    const int kk = k0 >> 8;          // kernel point (64-chunks never straddle)
    const int cb = (k0 & 255) >> 3;  // uint4 channel base within pixel row

    __syncthreads();   // prev MFMA reads done; s_ow visible on first iter
    // B staging: 2048 16B chunks; lds slot g forced = base+g*16; skew via source mapping
#pragma unroll
    for (int j = 0; j < 8; ++j) {
      const int g = tid + j * 256;
      const int c = g >> 8, rp = g & 255;
      const int n = (rp - 2 * c) & 255;
      load_lds16(Bt + (size_t)n * KC + k0 + c * 8, &s_b[g * 16]);
    }
    // A sampling: 192 units = 48 px x 4 groups of 16 ch (2 full uint4 from same 128B line)
    if (tid < 192) {
      const float2* owp = &s_ow[(ps * 9 + kk) * 4];
      float a[16];
#pragma unroll
      for (int t = 0; t < 16; ++t) a[t] = 0.f;
#pragma unroll
      for (int c2 = 0; c2 < 4; ++c2) {
        const float2 ow = owp[c2];
        const uint4* src = xpu + (size_t)__float_as_int(ow.x) + cb + grp * 2;
        const uint4 v0 = src[0], v1 = src[1];
        acc8(v0, ow.y, a);
        acc8(v1, ow.y, a + 8);
      }
      uint4 o0, o1;
      o0.x = pk2(a[0], a[1]);   o0.y = pk2(a[2], a[3]);
      o0.z = pk2(a[4], a[5]);   o0.w = pk2(a[6], a[7]);
      o1.x = pk2(a[8], a[9]);   o1.y = pk2(a[10], a[11]);
      o1.z = pk2(a[12], a[13]); o1.w = pk2(a[14], a[15]);
      char* dst = &s_a[ps * 144 + grp * 32];
      *(uint4*)dst = o0;
      *(uint4*)(dst + 16) = o1;
    }
    __syncthreads();   // A ds_writes + B DMA drained

    bf16x8 af[3][2], bfr[4][2];
#pragma unroll
    for (int mt = 0; mt < 3; ++mt)
#pragma unroll
      for (int c = 0; c < 2; ++c)
        af[mt][c] = *(const bf16x8*)&s_a[(mt * 16 + l16) * 144 + c * 64 + quad * 16];
#pragma unroll
    for (int nt = 0; nt < 4; ++nt)
#pragma unroll
      for (int c = 0; c < 2; ++c) {
        const int cc   = c * 4 + quad;
        const int n    = wave * 64 + nt * 16 + l16;
        const int slot = cc * 256 + ((n + 2 * cc) & 255);
        bfr[nt][c] = *(const bf16x8*)&s_b[slot * 16];
      }
#pragma unroll
    for (int c = 0; c < 2; ++c)
#pragma unroll
      for (int mt = 0; mt < 3; ++mt)
#pragma unroll
        for (int nt = 0; nt < 4; ++nt)
          acc[mt][nt] = __builtin_amdgcn_mfma_f32_16x16x32_bf16(af[mt][c], bfr[nt][c],
                                                                acc[mt][nt], 0, 0, 0);
  }

  // epilogue: C/D layout col=lane&15, row=quad*4+reg, + bias
#pragma unroll
  for (int mt = 0; mt < 3; ++mt) {
#pragma unroll
    for (int nt = 0; nt < 4; ++nt) {
      const int gm = m0 + mt * 16 + quad * 4;
      const int gn = wave * 64 + nt * 16 + l16;
      const float bs = bias[gn];
#pragma unroll
      for (int r = 0; r < 4; ++r)
        out[(size_t)(gm + r) * F + gn] = acc[mt][nt][r] + bs;
    }
  }
}

extern "C" void kernel_launch(void* const* d_in, const int* in_sizes, int n_in,
                              void* d_out, int out_size, void* d_ws, size_t ws_size,
                              hipStream_t stream) {
  const float* x    = (const float*)d_in[0];   // [4,96,96,256]
  const float* omk  = (const float*)d_in[1];   // [3,3,256,27]
  const float* omb  = (const float*)d_in[2];   // [27]
  const float* kern = (const float*)d_in[3];   // [2304,256]
  const float* bias = (const float*)d_in[4];   // [256]
  float* out = (float*)d_out;                  // [4,96,96,256]

  char* ws = (char*)d_ws;
  size_t off = 0;
  __hip_bfloat16* wt   = (__hip_bfloat16*)(ws + off); off += (size_t)F * KC * 2;           // 1,179,648
  __hip_bfloat16* xp   = (__hip_bfloat16*)(ws + off); off += (size_t)4 * HP * HP * C * 2;  // 19,668,992
  __hip_bfloat16* wom  = (__hip_bfloat16*)(ws + off); off += (size_t)32 * KC * 2;          // 147,456
  float*          pOm  = (float*)(ws + off);          off += (size_t)NP * 32 * 4;          // 4,718,592

  k_prep  <<<dim3(NB_PAD + NB_OMW + NB_WT + NB_ZERO), 256, 0, stream>>>(
      x, omk, kern, (uint4*)xp, wom, wt, (float4*)pOm);
  k_omgemm<<<dim3(NP / 128, 6), 256, 0, stream>>>(xp, wom, pOm);
  k_fused <<<dim3(NP / 48),     256, 0, stream>>>((const uint4*)xp, pOm, omb, wt, bias, out);
}